// Round 1
// baseline (213.702 us; speedup 1.0000x reference)
//
#include <hip/hip_runtime.h>
#include <cstdint>
#include <cstddef>

// ---------------------------------------------------------------------------
// MultiHeadAttention (B=2, S=2048, DIM=1024, H=16, HD=64), causal + RoPE.
// bf16 MFMA pipeline: cvt -> QKV gemm -> rope -> V-transpose -> flash attn ->
// out gemm (fp32 out). All fp32 accumulation.
// ---------------------------------------------------------------------------

typedef __bf16 bf16_t;
typedef __bf16 bf16x8 __attribute__((ext_vector_type(8)));
typedef __bf16 bf16x4 __attribute__((ext_vector_type(4)));
typedef float  f32x4  __attribute__((ext_vector_type(4)));

#define DEVFN __device__ __forceinline__

static constexpr int Bn  = 2;
static constexpr int S   = 2048;
static constexpr int DIM = 1024;
static constexpr int NH  = 16;
static constexpr int HD  = 64;
static constexpr int Mrows = Bn * S;        // 4096

DEVFN f32x4 mfma16(bf16x8 a, bf16x8 b, f32x4 c) {
  return __builtin_amdgcn_mfma_f32_16x16x32_bf16(a, b, c, 0, 0, 0);
}

// async global->LDS, 16B per lane. lds base must be wave-uniform; lanes land at
// base + lane*16.
DEVFN void gl_lds16(const bf16_t* g, bf16_t* l) {
  __builtin_amdgcn_global_load_lds(
      (const __attribute__((address_space(1))) unsigned*)g,
      (__attribute__((address_space(3))) unsigned*)l, 16, 0, 0);
}

// ---------------------------------------------------------------------------
__global__ __launch_bounds__(256) void k_cvt(const float* __restrict__ in,
                                             bf16_t* __restrict__ out, int n) {
  int i = (blockIdx.x * 256 + threadIdx.x) * 4;
  if (i >= n) return;
  float4 v = *(const float4*)(in + i);
  bf16x4 o = { (bf16_t)v.x, (bf16_t)v.y, (bf16_t)v.z, (bf16_t)v.w };
  *(bf16x4*)(out + i) = o;
}

__global__ __launch_bounds__(256) void k_tab(float2* __restrict__ tab) {
  int i = blockIdx.x * 256 + threadIdx.x;   // < S*32
  int s = i >> 5, d = i & 31;
  float th = (float)s * expf(-(2.0f * (float)d / 64.0f) * logf(10000.0f));
  tab[i] = make_float2(cosf(th), sinf(th));
}

// in-place rope on [Mrows][DIM] bf16, pairs interleaved within each 64-d head.
__global__ __launch_bounds__(256) void k_rope(bf16_t* __restrict__ X,
                                              const float2* __restrict__ tab,
                                              float scale) {
  int i = blockIdx.x * 256 + threadIdx.x;   // chunk of 8 elems, Mrows*DIM/8 total
  int row = i >> 7;                          // DIM/8 = 128 chunks per row
  int s = row & (S - 1);
  int dd = (i & 7) << 3;                     // within-head col base (chunks of 8)
  int p0 = dd >> 1;
  bf16x8 v = *(bf16x8*)(X + (size_t)i * 8);
  bf16x8 o;
#pragma unroll
  for (int j = 0; j < 4; ++j) {
    float x1 = (float)v[2 * j], x2 = (float)v[2 * j + 1];
    float2 cs = tab[s * 32 + p0 + j];
    o[2 * j]     = (bf16_t)((x1 * cs.x - x2 * cs.y) * scale);
    o[2 * j + 1] = (bf16_t)((x1 * cs.y + x2 * cs.x) * scale);
  }
  *(bf16x8*)(X + (size_t)i * 8) = o;
}

// V [b][s][h][d] -> VT [b*h][d][s]
__global__ __launch_bounds__(256) void k_trans(const bf16_t* __restrict__ Vin,
                                               bf16_t* __restrict__ VT) {
  __shared__ __align__(16) bf16_t tile[64][72];
  int s0 = blockIdx.x * 64, bh = blockIdx.y;
  int b = bh >> 4, h = bh & 15;
  int t = threadIdx.x;
#pragma unroll
  for (int it = 0; it < 2; ++it) {
    int sl = (t >> 3) + it * 32, d0 = (t & 7) << 3;
    *(bf16x8*)&tile[sl][d0] =
        *(const bf16x8*)(Vin + (size_t)(b * S + s0 + sl) * DIM + h * HD + d0);
  }
  __syncthreads();
  int d = t >> 2, c0 = (t & 3) * 16;
  bf16_t buf[16];
#pragma unroll
  for (int j = 0; j < 16; ++j) buf[j] = tile[c0 + j][d];
  bf16_t* op = VT + ((size_t)bh * HD + d) * S + s0 + c0;
  *(bf16x8*)op = *(bf16x8*)&buf[0];
  *(bf16x8*)(op + 8) = *(bf16x8*)&buf[8];
}

// ---------------------------------------------------------------------------
// NT GEMM: Out[m][n] = sum_k A[m][k] * Bw[n][k] + bias[n].
// 128x128 tile, BK=32, 4 waves each 64x64 (4x4 of 16x16x32 MFMA).
// grid.z selects among up to 3 (B,bias,Out) triples (fused QKV).
template <bool OUTF32>
__global__ __launch_bounds__(256) void k_gemm(
    const bf16_t* __restrict__ A,
    const bf16_t* __restrict__ B0, const bf16_t* __restrict__ B1,
    const bf16_t* __restrict__ B2,
    const float* __restrict__ c0, const float* __restrict__ c1,
    const float* __restrict__ c2,
    void* O0, void* O1, void* O2, int Mg, int Ng, int Kg) {
  const bf16_t* Bw = blockIdx.z == 0 ? B0 : (blockIdx.z == 1 ? B1 : B2);
  const float* bias = blockIdx.z == 0 ? c0 : (blockIdx.z == 1 ? c1 : c2);
  void* Ov = blockIdx.z == 0 ? O0 : (blockIdx.z == 1 ? O1 : O2);

  __shared__ __align__(16) bf16_t Al[128 * 32];
  __shared__ __align__(16) bf16_t Bl[128 * 32];
  const int t = threadIdx.x, w = t >> 6, l = t & 63;
  const int lr = l & 15, lc = l >> 4;
  const int m0 = blockIdx.y * 128, n0 = blockIdx.x * 128;
  const int wr = w >> 1, wc = w & 1;
  f32x4 acc[4][4] = {};

  for (int k0 = 0; k0 < Kg; k0 += 32) {
    __syncthreads();
#pragma unroll
    for (int ld = 0; ld < 2; ++ld) {
      int c = t + ld * 256;            // 16B chunk id; row=c>>2, col8=(c&3)*8
      int row = c >> 2, j = (c & 3) << 3;
      bf16_t* dstA = Al + (size_t)(w * 64 + ld * 256) * 8;
      bf16_t* dstB = Bl + (size_t)(w * 64 + ld * 256) * 8;
      gl_lds16(A + (size_t)(m0 + row) * Kg + k0 + j, dstA);
      gl_lds16(Bw + (size_t)(n0 + row) * Kg + k0 + j, dstB);
    }
    __syncthreads();
    bf16x8 af[4], bfr[4];
#pragma unroll
    for (int mi = 0; mi < 4; ++mi)
      af[mi] = *(const bf16x8*)(Al + (wr * 64 + mi * 16 + lr) * 32 + lc * 8);
#pragma unroll
    for (int ni = 0; ni < 4; ++ni)
      bfr[ni] = *(const bf16x8*)(Bl + (wc * 64 + ni * 16 + lr) * 32 + lc * 8);
#pragma unroll
    for (int mi = 0; mi < 4; ++mi)
#pragma unroll
      for (int ni = 0; ni < 4; ++ni)
        acc[mi][ni] = mfma16(af[mi], bfr[ni], acc[mi][ni]);
  }

#pragma unroll
  for (int ni = 0; ni < 4; ++ni) {
    int col = n0 + wc * 64 + ni * 16 + lr;
    float bv = bias[col];
#pragma unroll
    for (int mi = 0; mi < 4; ++mi) {
#pragma unroll
      for (int r = 0; r < 4; ++r) {
        int row = m0 + wr * 64 + mi * 16 + lc * 4 + r;
        float v = acc[mi][ni][r] + bv;
        if (OUTF32)
          ((float*)Ov)[(size_t)row * Ng + col] = v;
        else
          ((bf16_t*)Ov)[(size_t)row * Ng + col] = (bf16_t)v;
      }
    }
  }
}

// ---------------------------------------------------------------------------
// Causal flash attention. Q pre-scaled by 1/8 (folded into rope).
// grid: (S/64 q-tiles, B*NH). 4 waves x 16 q-rows. K/VT tiles 64x64 in LDS,
// staged linearly via global_load_lds with pre-swizzled SOURCE chunk, read
// with addr = row*128 + (colbyte ^ ((row&7)<<4))  (T2 XOR swizzle).
__global__ __launch_bounds__(256) void k_attn(const bf16_t* __restrict__ Q,
                                              const bf16_t* __restrict__ Kc,
                                              const bf16_t* __restrict__ VT,
                                              bf16_t* __restrict__ O) {
  __shared__ __align__(16) bf16_t Kl[64 * 64];
  __shared__ __align__(16) bf16_t Vl[64 * 64];
  __shared__ __align__(16) bf16_t Pl[4][16 * 64];
  const int t = threadIdx.x, w = t >> 6, l = t & 63;
  const int lr = l & 15, lc = l >> 4;
  const int q0 = blockIdx.x * 64;
  const int bh = blockIdx.y, b = bh >> 4, h = bh & 15;

  bf16x8 qf[2];
  {
    const bf16_t* qp = Q + (size_t)(b * S + q0 + w * 16 + lr) * DIM + h * HD + lc * 8;
    qf[0] = *(const bf16x8*)qp;
    qf[1] = *(const bf16x8*)(qp + 32);
  }
  f32x4 o[4] = {};
  float rowmax[4] = { -INFINITY, -INFINITY, -INFINITY, -INFINITY };
  float rowsum[4] = { 0.f, 0.f, 0.f, 0.f };

  const int nt = (q0 >> 6) + 1;
  for (int it = 0; it < nt; ++it) {
    const int k0 = it * 64;
    __syncthreads();
#pragma unroll
    for (int ld = 0; ld < 2; ++ld) {
      int c = t + ld * 256;             // chunk: row=c>>3, in-row chunk=c&7
      int row = c >> 3;
      int j = ((c & 7) ^ (row & 7)) << 3;   // pre-swizzled source chunk
      bf16_t* dstK = Kl + (size_t)(w * 64 + ld * 256) * 8;
      bf16_t* dstV = Vl + (size_t)(w * 64 + ld * 256) * 8;
      gl_lds16(Kc + (size_t)(b * S + k0 + row) * DIM + h * HD + j, dstK);
      gl_lds16(VT + ((size_t)bh * HD + row) * S + k0 + j, dstV);
    }
    __syncthreads();

    // QK^T -> s[ni] (16 q-rows x 64 k-cols per wave)
    f32x4 s[4] = {};
#pragma unroll
    for (int ks = 0; ks < 2; ++ks) {
#pragma unroll
      for (int ni = 0; ni < 4; ++ni) {
        int row = ni * 16 + lr;
        int off = (ks * 64 + lc * 16) ^ ((row & 7) << 4);
        bf16x8 kf = *(const bf16x8*)((const char*)Kl + row * 128 + off);
        s[ni] = mfma16(qf[ks], kf, s[ni]);
      }
    }
    if (k0 == q0) {  // diagonal tile: mask col > row
#pragma unroll
      for (int ni = 0; ni < 4; ++ni)
#pragma unroll
        for (int r = 0; r < 4; ++r)
          if (k0 + ni * 16 + lr > q0 + w * 16 + lc * 4 + r) s[ni][r] = -INFINITY;
    }

    // online softmax (rows live across 16 lanes sharing lc)
#pragma unroll
    for (int r = 0; r < 4; ++r) {
      float pm = fmaxf(fmaxf(s[0][r], s[1][r]), fmaxf(s[2][r], s[3][r]));
#pragma unroll
      for (int d = 1; d < 16; d <<= 1) pm = fmaxf(pm, __shfl_xor(pm, d));
      float mn = fmaxf(rowmax[r], pm);
      float alpha = __expf(rowmax[r] - mn);
      rowmax[r] = mn;
      float rs = 0.f;
#pragma unroll
      for (int ni = 0; ni < 4; ++ni) {
        float p = __expf(s[ni][r] - mn);
        s[ni][r] = p;
        rs += p;
      }
#pragma unroll
      for (int d = 1; d < 16; d <<= 1) rs += __shfl_xor(rs, d);
      rowsum[r] = rowsum[r] * alpha + rs;
#pragma unroll
      for (int ni = 0; ni < 4; ++ni) o[ni][r] *= alpha;
    }

    // P (bf16) -> wave-private LDS, swizzled; same-wave, no barrier needed.
#pragma unroll
    for (int ni = 0; ni < 4; ++ni)
#pragma unroll
      for (int r = 0; r < 4; ++r) {
        int prow = lc * 4 + r;
        int pcol = ni * 16 + lr;
        int baddr = prow * 128 + ((pcol * 2) ^ ((prow & 7) << 4));
        *(bf16_t*)((char*)&Pl[w][0] + baddr) = (bf16_t)s[ni][r];
      }

    // PV: o[ni] += P(16x64) * V(64x64)
#pragma unroll
    for (int ks = 0; ks < 2; ++ks) {
      int off = ks * 64 + lc * 16;
      bf16x8 pa = *(const bf16x8*)((const char*)&Pl[w][0] + lr * 128 +
                                   (off ^ ((lr & 7) << 4)));
#pragma unroll
      for (int ni = 0; ni < 4; ++ni) {
        int vrow = ni * 16 + lr;
        bf16x8 vb = *(const bf16x8*)((const char*)Vl + vrow * 128 +
                                     (off ^ ((vrow & 7) << 4)));
        o[ni] = mfma16(pa, vb, o[ni]);
      }
    }
  }

#pragma unroll
  for (int ni = 0; ni < 4; ++ni)
#pragma unroll
    for (int r = 0; r < 4; ++r) {
      int qr = q0 + w * 16 + lc * 4 + r;
      float v = o[ni][r] / rowsum[r];
      O[(size_t)(b * S + qr) * DIM + h * HD + ni * 16 + lr] = (bf16_t)v;
    }
}

// ---------------------------------------------------------------------------
extern "C" void kernel_launch(void* const* d_in, const int* in_sizes, int n_in,
                              void* d_out, int out_size, void* d_ws,
                              size_t ws_size, hipStream_t stream) {
  const float* x  = (const float*)d_in[0];
  const float* wq = (const float*)d_in[1];
  const float* bq = (const float*)d_in[2];
  const float* wk = (const float*)d_in[3];
  const float* bk = (const float*)d_in[4];
  const float* wv = (const float*)d_in[5];
  const float* bv = (const float*)d_in[6];
  const float* wo = (const float*)d_in[7];
  const float* bo = (const float*)d_in[8];

  const size_t MD = (size_t)Mrows * DIM;   // 4194304
  const size_t WD = (size_t)DIM * DIM;     // 1048576
  bf16_t* W = (bf16_t*)d_ws;
  bf16_t* x_bf  = W;
  bf16_t* wq_bf = x_bf + MD;
  bf16_t* wk_bf = wq_bf + WD;
  bf16_t* wv_bf = wk_bf + WD;
  bf16_t* wo_bf = wv_bf + WD;
  bf16_t* q_lin = wo_bf + WD;
  bf16_t* k_lin = q_lin + MD;
  bf16_t* v_lin = k_lin + MD;
  bf16_t* vT    = v_lin + MD;
  float2* tab   = (float2*)(vT + MD);
  bf16_t* attn_out = v_lin;  // reuse: v_lin dead after transpose

  k_cvt<<<4096, 256, 0, stream>>>(x, x_bf, (int)MD);
  k_cvt<<<1024, 256, 0, stream>>>(wq, wq_bf, (int)WD);
  k_cvt<<<1024, 256, 0, stream>>>(wk, wk_bf, (int)WD);
  k_cvt<<<1024, 256, 0, stream>>>(wv, wv_bf, (int)WD);
  k_cvt<<<1024, 256, 0, stream>>>(wo, wo_bf, (int)WD);
  k_tab<<<256, 256, 0, stream>>>(tab);

  // fused QKV projections
  k_gemm<false><<<dim3(DIM / 128, Mrows / 128, 3), 256, 0, stream>>>(
      x_bf, wq_bf, wk_bf, wv_bf, bq, bk, bv, q_lin, k_lin, v_lin, Mrows, DIM,
      DIM);

  k_rope<<<2048, 256, 0, stream>>>(q_lin, tab, 0.125f);  // fold 1/sqrt(64)
  k_rope<<<2048, 256, 0, stream>>>(k_lin, tab, 1.0f);
  k_trans<<<dim3(S / 64, Bn * NH), 256, 0, stream>>>(v_lin, vT);

  k_attn<<<dim3(S / 64, Bn * NH), 256, 0, stream>>>(q_lin, k_lin, vT, attn_out);

  // output projection, fp32 out + bias straight to d_out
  k_gemm<true><<<dim3(DIM / 128, Mrows / 128, 1), 256, 0, stream>>>(
      attn_out, wo_bf, wo_bf, wo_bf, bo, bo, bo, d_out, d_out, d_out, Mrows,
      DIM, DIM);
}

// Round 2
// 166.544 us; speedup vs baseline: 1.2832x; 1.2832x over previous
//
#include <hip/hip_runtime.h>
#include <cstdint>
#include <cstddef>

// ---------------------------------------------------------------------------
// MultiHeadAttention (B=2, S=2048, DIM=1024, H=16, HD=64), causal + RoPE.
// bf16 MFMA pipeline: cvt -> QKV gemm -> rope -> V-transpose -> flash attn ->
// out gemm (fp32 out). All fp32 accumulation.
// R2: attn rewritten — paired q-tiles (uniform work), double-buffered K/V with
// counted vmcnt + raw barriers, setprio around MFMA.
// ---------------------------------------------------------------------------

typedef __bf16 bf16_t;
typedef __bf16 bf16x8 __attribute__((ext_vector_type(8)));
typedef __bf16 bf16x4 __attribute__((ext_vector_type(4)));
typedef float  f32x4  __attribute__((ext_vector_type(4)));

#define DEVFN __device__ __forceinline__

static constexpr int Bn  = 2;
static constexpr int S   = 2048;
static constexpr int DIM = 1024;
static constexpr int NH  = 16;
static constexpr int HD  = 64;
static constexpr int Mrows = Bn * S;        // 4096

DEVFN f32x4 mfma16(bf16x8 a, bf16x8 b, f32x4 c) {
  return __builtin_amdgcn_mfma_f32_16x16x32_bf16(a, b, c, 0, 0, 0);
}

// async global->LDS, 16B per lane. lds base must be wave-uniform; lanes land at
// base + lane*16.
DEVFN void gl_lds16(const bf16_t* g, bf16_t* l) {
  __builtin_amdgcn_global_load_lds(
      (const __attribute__((address_space(1))) unsigned*)g,
      (__attribute__((address_space(3))) unsigned*)l, 16, 0, 0);
}

// ---------------------------------------------------------------------------
__global__ __launch_bounds__(256) void k_cvt(const float* __restrict__ in,
                                             bf16_t* __restrict__ out, int n) {
  int i = (blockIdx.x * 256 + threadIdx.x) * 4;
  if (i >= n) return;
  float4 v = *(const float4*)(in + i);
  bf16x4 o = { (bf16_t)v.x, (bf16_t)v.y, (bf16_t)v.z, (bf16_t)v.w };
  *(bf16x4*)(out + i) = o;
}

__global__ __launch_bounds__(256) void k_tab(float2* __restrict__ tab) {
  int i = blockIdx.x * 256 + threadIdx.x;   // < S*32
  int s = i >> 5, d = i & 31;
  float th = (float)s * expf(-(2.0f * (float)d / 64.0f) * logf(10000.0f));
  tab[i] = make_float2(cosf(th), sinf(th));
}

// in-place rope on [Mrows][DIM] bf16, pairs interleaved within each 64-d head.
__global__ __launch_bounds__(256) void k_rope(bf16_t* __restrict__ X,
                                              const float2* __restrict__ tab,
                                              float scale) {
  int i = blockIdx.x * 256 + threadIdx.x;   // chunk of 8 elems, Mrows*DIM/8 total
  int row = i >> 7;                          // DIM/8 = 128 chunks per row
  int s = row & (S - 1);
  int dd = (i & 7) << 3;                     // within-head col base (chunks of 8)
  int p0 = dd >> 1;
  bf16x8 v = *(bf16x8*)(X + (size_t)i * 8);
  bf16x8 o;
#pragma unroll
  for (int j = 0; j < 4; ++j) {
    float x1 = (float)v[2 * j], x2 = (float)v[2 * j + 1];
    float2 cs = tab[s * 32 + p0 + j];
    o[2 * j]     = (bf16_t)((x1 * cs.x - x2 * cs.y) * scale);
    o[2 * j + 1] = (bf16_t)((x1 * cs.y + x2 * cs.x) * scale);
  }
  *(bf16x8*)(X + (size_t)i * 8) = o;
}

// V [b][s][h][d] -> VT [b*h][d][s]
__global__ __launch_bounds__(256) void k_trans(const bf16_t* __restrict__ Vin,
                                               bf16_t* __restrict__ VT) {
  __shared__ __align__(16) bf16_t tile[64][72];
  int s0 = blockIdx.x * 64, bh = blockIdx.y;
  int b = bh >> 4, h = bh & 15;
  int t = threadIdx.x;
#pragma unroll
  for (int it = 0; it < 2; ++it) {
    int sl = (t >> 3) + it * 32, d0 = (t & 7) << 3;
    *(bf16x8*)&tile[sl][d0] =
        *(const bf16x8*)(Vin + (size_t)(b * S + s0 + sl) * DIM + h * HD + d0);
  }
  __syncthreads();
  int d = t >> 2, c0 = (t & 3) * 16;
  bf16_t buf[16];
#pragma unroll
  for (int j = 0; j < 16; ++j) buf[j] = tile[c0 + j][d];
  bf16_t* op = VT + ((size_t)bh * HD + d) * S + s0 + c0;
  *(bf16x8*)op = *(bf16x8*)&buf[0];
  *(bf16x8*)(op + 8) = *(bf16x8*)&buf[8];
}

// ---------------------------------------------------------------------------
// NT GEMM: Out[m][n] = sum_k A[m][k] * Bw[n][k] + bias[n].
// 128x128 tile, BK=32, 4 waves each 64x64 (4x4 of 16x16x32 MFMA).
// grid.z selects among up to 3 (B,bias,Out) triples (fused QKV).
template <bool OUTF32>
__global__ __launch_bounds__(256) void k_gemm(
    const bf16_t* __restrict__ A,
    const bf16_t* __restrict__ B0, const bf16_t* __restrict__ B1,
    const bf16_t* __restrict__ B2,
    const float* __restrict__ c0, const float* __restrict__ c1,
    const float* __restrict__ c2,
    void* O0, void* O1, void* O2, int Mg, int Ng, int Kg) {
  const bf16_t* Bw = blockIdx.z == 0 ? B0 : (blockIdx.z == 1 ? B1 : B2);
  const float* bias = blockIdx.z == 0 ? c0 : (blockIdx.z == 1 ? c1 : c2);
  void* Ov = blockIdx.z == 0 ? O0 : (blockIdx.z == 1 ? O1 : O2);

  __shared__ __align__(16) bf16_t Al[128 * 32];
  __shared__ __align__(16) bf16_t Bl[128 * 32];
  const int t = threadIdx.x, w = t >> 6, l = t & 63;
  const int lr = l & 15, lc = l >> 4;
  const int m0 = blockIdx.y * 128, n0 = blockIdx.x * 128;
  const int wr = w >> 1, wc = w & 1;
  f32x4 acc[4][4] = {};

  for (int k0 = 0; k0 < Kg; k0 += 32) {
    __syncthreads();
#pragma unroll
    for (int ld = 0; ld < 2; ++ld) {
      int c = t + ld * 256;            // 16B chunk id; row=c>>2, col8=(c&3)*8
      int row = c >> 2, j = (c & 3) << 3;
      bf16_t* dstA = Al + (size_t)(w * 64 + ld * 256) * 8;
      bf16_t* dstB = Bl + (size_t)(w * 64 + ld * 256) * 8;
      gl_lds16(A + (size_t)(m0 + row) * Kg + k0 + j, dstA);
      gl_lds16(Bw + (size_t)(n0 + row) * Kg + k0 + j, dstB);
    }
    __syncthreads();
    bf16x8 af[4], bfr[4];
#pragma unroll
    for (int mi = 0; mi < 4; ++mi)
      af[mi] = *(const bf16x8*)(Al + (wr * 64 + mi * 16 + lr) * 32 + lc * 8);
#pragma unroll
    for (int ni = 0; ni < 4; ++ni)
      bfr[ni] = *(const bf16x8*)(Bl + (wc * 64 + ni * 16 + lr) * 32 + lc * 8);
#pragma unroll
    for (int mi = 0; mi < 4; ++mi)
#pragma unroll
      for (int ni = 0; ni < 4; ++ni)
        acc[mi][ni] = mfma16(af[mi], bfr[ni], acc[mi][ni]);
  }

#pragma unroll
  for (int ni = 0; ni < 4; ++ni) {
    int col = n0 + wc * 64 + ni * 16 + lr;
    float bv = bias[col];
#pragma unroll
    for (int mi = 0; mi < 4; ++mi) {
#pragma unroll
      for (int r = 0; r < 4; ++r) {
        int row = m0 + wr * 64 + mi * 16 + lc * 4 + r;
        float v = acc[mi][ni][r] + bv;
        if (OUTF32)
          ((float*)Ov)[(size_t)row * Ng + col] = v;
        else
          ((bf16_t*)Ov)[(size_t)row * Ng + col] = (bf16_t)v;
      }
    }
  }
}

// ---------------------------------------------------------------------------
// Causal flash attention, R2.
// grid: (16 q-tile pairs, B*NH). Block handles q-tiles a and 31-a sequentially
// -> uniform 33 KV-iterations per block. K/VT 64x64 tiles double-buffered in
// LDS via global_load_lds (linear dest, pre-swizzled global source chunk),
// read with addr = row*128 + (colbyte ^ ((row&7)<<4)) (T2 XOR swizzle).
// Counted s_waitcnt vmcnt(4) + raw s_barrier keeps next tile's loads in
// flight under current tile's compute.
DEVFN void stage_kv(const bf16_t* __restrict__ Kc,
                    const bf16_t* __restrict__ VT, bf16_t* Kb, bf16_t* Vb,
                    int b, int bh, int h, int k0, int t, int w) {
#pragma unroll
  for (int ld = 0; ld < 2; ++ld) {
    int c = t + ld * 256;             // chunk: row=c>>3, in-row chunk=c&7
    int row = c >> 3;
    int j = ((c & 7) ^ (row & 7)) << 3;   // pre-swizzled source chunk
    bf16_t* dstK = Kb + (size_t)(w * 64 + ld * 256) * 8;
    bf16_t* dstV = Vb + (size_t)(w * 64 + ld * 256) * 8;
    gl_lds16(Kc + (size_t)(b * S + k0 + row) * DIM + h * HD + j, dstK);
    gl_lds16(VT + ((size_t)bh * HD + row) * S + k0 + j, dstV);
  }
}

__global__ __launch_bounds__(256) void k_attn(const bf16_t* __restrict__ Q,
                                              const bf16_t* __restrict__ Kc,
                                              const bf16_t* __restrict__ VT,
                                              bf16_t* __restrict__ O) {
  __shared__ __align__(16) bf16_t Kl[2][64 * 64];
  __shared__ __align__(16) bf16_t Vl[2][64 * 64];
  __shared__ __align__(16) bf16_t Pl[4][16 * 64];
  const int t = threadIdx.x, w = t >> 6, l = t & 63;
  const int lr = l & 15, lc = l >> 4;
  const int a = blockIdx.x;
  const int bh = blockIdx.y, b = bh >> 4, h = bh & 15;

#pragma unroll 1
  for (int pi = 0; pi < 2; ++pi) {
    const int tile = (pi == 0) ? a : 31 - a;
    const int q0 = tile * 64;
    const int nt = tile + 1;

    bf16x8 qf[2];
    {
      const bf16_t* qp =
          Q + (size_t)(b * S + q0 + w * 16 + lr) * DIM + h * HD + lc * 8;
      qf[0] = *(const bf16x8*)qp;
      qf[1] = *(const bf16x8*)(qp + 32);
    }
    f32x4 o[4] = {};
    float rowmax[4] = { -INFINITY, -INFINITY, -INFINITY, -INFINITY };
    float rowsum[4] = { 0.f, 0.f, 0.f, 0.f };

    // prologue: stage tile 0, drain, barrier
    stage_kv(Kc, VT, &Kl[0][0], &Vl[0][0], b, bh, h, 0, t, w);
    asm volatile("s_waitcnt vmcnt(0)" ::: "memory");
    __builtin_amdgcn_s_barrier();
    __builtin_amdgcn_sched_barrier(0);

#pragma unroll 1
    for (int it = 0; it < nt; ++it) {
      const int cur = it & 1;
      const bf16_t* Kb = &Kl[cur][0];
      const bf16_t* Vb = &Vl[cur][0];
      if (it + 1 < nt) {
        stage_kv(Kc, VT, &Kl[cur ^ 1][0], &Vl[cur ^ 1][0], b, bh, h,
                 (it + 1) * 64, t, w);
        asm volatile("s_waitcnt vmcnt(4)" ::: "memory");
      } else {
        asm volatile("s_waitcnt vmcnt(0)" ::: "memory");
      }
      __builtin_amdgcn_s_barrier();
      __builtin_amdgcn_sched_barrier(0);

      // QK^T -> s[ni] (16 q-rows x 64 k-cols per wave)
      f32x4 s[4] = {};
      __builtin_amdgcn_s_setprio(1);
#pragma unroll
      for (int ks = 0; ks < 2; ++ks) {
#pragma unroll
        for (int ni = 0; ni < 4; ++ni) {
          int row = ni * 16 + lr;
          int off = (ks * 64 + lc * 16) ^ ((row & 7) << 4);
          bf16x8 kf = *(const bf16x8*)((const char*)Kb + row * 128 + off);
          s[ni] = mfma16(qf[ks], kf, s[ni]);
        }
      }
      __builtin_amdgcn_s_setprio(0);

      const int k0 = it * 64;
      if (k0 == q0) {  // diagonal tile: mask col > row
#pragma unroll
        for (int ni = 0; ni < 4; ++ni)
#pragma unroll
          for (int r = 0; r < 4; ++r)
            if (k0 + ni * 16 + lr > q0 + w * 16 + lc * 4 + r)
              s[ni][r] = -INFINITY;
      }

      // online softmax (rows live across 16 lanes sharing lc)
#pragma unroll
      for (int r = 0; r < 4; ++r) {
        float pm = fmaxf(fmaxf(s[0][r], s[1][r]), fmaxf(s[2][r], s[3][r]));
#pragma unroll
        for (int d = 1; d < 16; d <<= 1) pm = fmaxf(pm, __shfl_xor(pm, d));
        float mn = fmaxf(rowmax[r], pm);
        float alpha = __expf(rowmax[r] - mn);
        rowmax[r] = mn;
        float rs = 0.f;
#pragma unroll
        for (int ni = 0; ni < 4; ++ni) {
          float p = __expf(s[ni][r] - mn);
          s[ni][r] = p;
          rs += p;
        }
#pragma unroll
        for (int d = 1; d < 16; d <<= 1) rs += __shfl_xor(rs, d);
        rowsum[r] = rowsum[r] * alpha + rs;
#pragma unroll
        for (int ni = 0; ni < 4; ++ni) o[ni][r] *= alpha;
      }

      // P (bf16) -> wave-private LDS, swizzled; same-wave, no barrier needed.
#pragma unroll
      for (int ni = 0; ni < 4; ++ni)
#pragma unroll
        for (int r = 0; r < 4; ++r) {
          int prow = lc * 4 + r;
          int pcol = ni * 16 + lr;
          int baddr = prow * 128 + ((pcol * 2) ^ ((prow & 7) << 4));
          *(bf16_t*)((char*)&Pl[w][0] + baddr) = (bf16_t)s[ni][r];
        }

      // PV: o[ni] += P(16x64) * V(64x64)
      __builtin_amdgcn_s_setprio(1);
#pragma unroll
      for (int ks = 0; ks < 2; ++ks) {
        int off = ks * 64 + lc * 16;
        bf16x8 pa = *(const bf16x8*)((const char*)&Pl[w][0] + lr * 128 +
                                     (off ^ ((lr & 7) << 4)));
#pragma unroll
        for (int ni = 0; ni < 4; ++ni) {
          int vrow = ni * 16 + lr;
          bf16x8 vb = *(const bf16x8*)((const char*)Vb + vrow * 128 +
                                       (off ^ ((vrow & 7) << 4)));
          o[ni] = mfma16(pa, vb, o[ni]);
        }
      }
      __builtin_amdgcn_s_setprio(0);

      __builtin_amdgcn_s_barrier();   // compute done before next stage overwrite
    }

#pragma unroll
    for (int ni = 0; ni < 4; ++ni)
#pragma unroll
      for (int r = 0; r < 4; ++r) {
        int qr = q0 + w * 16 + lc * 4 + r;
        float v = o[ni][r] / rowsum[r];
        O[(size_t)(b * S + qr) * DIM + h * HD + ni * 16 + lr] = (bf16_t)v;
      }
  }
}

// ---------------------------------------------------------------------------
extern "C" void kernel_launch(void* const* d_in, const int* in_sizes, int n_in,
                              void* d_out, int out_size, void* d_ws,
                              size_t ws_size, hipStream_t stream) {
  const float* x  = (const float*)d_in[0];
  const float* wq = (const float*)d_in[1];
  const float* bq = (const float*)d_in[2];
  const float* wk = (const float*)d_in[3];
  const float* bk = (const float*)d_in[4];
  const float* wv = (const float*)d_in[5];
  const float* bv = (const float*)d_in[6];
  const float* wo = (const float*)d_in[7];
  const float* bo = (const float*)d_in[8];

  const size_t MD = (size_t)Mrows * DIM;   // 4194304
  const size_t WD = (size_t)DIM * DIM;     // 1048576
  bf16_t* W = (bf16_t*)d_ws;
  bf16_t* x_bf  = W;
  bf16_t* wq_bf = x_bf + MD;
  bf16_t* wk_bf = wq_bf + WD;
  bf16_t* wv_bf = wk_bf + WD;
  bf16_t* wo_bf = wv_bf + WD;
  bf16_t* q_lin = wo_bf + WD;
  bf16_t* k_lin = q_lin + MD;
  bf16_t* v_lin = k_lin + MD;
  bf16_t* vT    = v_lin + MD;
  float2* tab   = (float2*)(vT + MD);
  bf16_t* attn_out = v_lin;  // reuse: v_lin dead after transpose

  k_cvt<<<4096, 256, 0, stream>>>(x, x_bf, (int)MD);
  k_cvt<<<1024, 256, 0, stream>>>(wq, wq_bf, (int)WD);
  k_cvt<<<1024, 256, 0, stream>>>(wk, wk_bf, (int)WD);
  k_cvt<<<1024, 256, 0, stream>>>(wv, wv_bf, (int)WD);
  k_cvt<<<1024, 256, 0, stream>>>(wo, wo_bf, (int)WD);
  k_tab<<<256, 256, 0, stream>>>(tab);

  // fused QKV projections
  k_gemm<false><<<dim3(DIM / 128, Mrows / 128, 3), 256, 0, stream>>>(
      x_bf, wq_bf, wk_bf, wv_bf, bq, bk, bv, q_lin, k_lin, v_lin, Mrows, DIM,
      DIM);

  k_rope<<<2048, 256, 0, stream>>>(q_lin, tab, 0.125f);  // fold 1/sqrt(64)
  k_rope<<<2048, 256, 0, stream>>>(k_lin, tab, 1.0f);
  k_trans<<<dim3(S / 64, Bn * NH), 256, 0, stream>>>(v_lin, vT);

  k_attn<<<dim3(16, Bn * NH), 256, 0, stream>>>(q_lin, k_lin, vT, attn_out);

  // output projection, fp32 out + bias straight to d_out
  k_gemm<true><<<dim3(DIM / 128, Mrows / 128, 1), 256, 0, stream>>>(
      attn_out, wo_bf, wo_bf, wo_bf, bo, bo, bo, d_out, d_out, d_out, Mrows,
      DIM, DIM);
}

// Round 4
// 143.067 us; speedup vs baseline: 1.4937x; 1.1641x over previous
//
#include <hip/hip_runtime.h>
#include <cstdint>
#include <cstddef>

// ---------------------------------------------------------------------------
// MultiHeadAttention (B=2, S=2048, DIM=1024, H=16, HD=64), causal + RoPE.
// bf16 MFMA pipeline: cvt -> QKV gemm -> rope -> V-transpose -> flash attn ->
// out gemm (fp32 out). All fp32 accumulation.
// R4: fix R3 diagonal mask (k_local > w*16 + lr, the wave-q offset was
// dropped in the swapped-QK^T translation). Rest identical to R3.
// ---------------------------------------------------------------------------

typedef __bf16 bf16_t;
typedef __bf16 bf16x8 __attribute__((ext_vector_type(8)));
typedef __bf16 bf16x4 __attribute__((ext_vector_type(4)));
typedef float  f32x4  __attribute__((ext_vector_type(4)));

#define DEVFN __device__ __forceinline__

static constexpr int Bn  = 2;
static constexpr int S   = 2048;
static constexpr int DIM = 1024;
static constexpr int NH  = 16;
static constexpr int HD  = 64;
static constexpr int Mrows = Bn * S;        // 4096

DEVFN f32x4 mfma16(bf16x8 a, bf16x8 b, f32x4 c) {
  return __builtin_amdgcn_mfma_f32_16x16x32_bf16(a, b, c, 0, 0, 0);
}

// async global->LDS, 16B per lane. lds base must be wave-uniform; lanes land at
// base + lane*16.
DEVFN void gl_lds16(const bf16_t* g, bf16_t* l) {
  __builtin_amdgcn_global_load_lds(
      (const __attribute__((address_space(1))) unsigned*)g,
      (__attribute__((address_space(3))) unsigned*)l, 16, 0, 0);
}

// ---------------------------------------------------------------------------
__global__ __launch_bounds__(256) void k_cvt(const float* __restrict__ in,
                                             bf16_t* __restrict__ out, int n) {
  int i = (blockIdx.x * 256 + threadIdx.x) * 4;
  if (i >= n) return;
  float4 v = *(const float4*)(in + i);
  bf16x4 o = { (bf16_t)v.x, (bf16_t)v.y, (bf16_t)v.z, (bf16_t)v.w };
  *(bf16x4*)(out + i) = o;
}

__global__ __launch_bounds__(256) void k_tab(float2* __restrict__ tab) {
  int i = blockIdx.x * 256 + threadIdx.x;   // < S*32
  int s = i >> 5, d = i & 31;
  float th = (float)s * expf(-(2.0f * (float)d / 64.0f) * logf(10000.0f));
  tab[i] = make_float2(cosf(th), sinf(th));
}

// in-place rope on [Mrows][DIM] bf16, pairs interleaved within each 64-d head.
__global__ __launch_bounds__(256) void k_rope(bf16_t* __restrict__ X,
                                              const float2* __restrict__ tab,
                                              float scale) {
  int i = blockIdx.x * 256 + threadIdx.x;   // chunk of 8 elems, Mrows*DIM/8 total
  int row = i >> 7;                          // DIM/8 = 128 chunks per row
  int s = row & (S - 1);
  int dd = (i & 7) << 3;                     // within-head col base (chunks of 8)
  int p0 = dd >> 1;
  bf16x8 v = *(bf16x8*)(X + (size_t)i * 8);
  bf16x8 o;
#pragma unroll
  for (int j = 0; j < 4; ++j) {
    float x1 = (float)v[2 * j], x2 = (float)v[2 * j + 1];
    float2 cs = tab[s * 32 + p0 + j];
    o[2 * j]     = (bf16_t)((x1 * cs.x - x2 * cs.y) * scale);
    o[2 * j + 1] = (bf16_t)((x1 * cs.y + x2 * cs.x) * scale);
  }
  *(bf16x8*)(X + (size_t)i * 8) = o;
}

// V [b][s][h][d] -> VT [b*h][d][s]
__global__ __launch_bounds__(256) void k_trans(const bf16_t* __restrict__ Vin,
                                               bf16_t* __restrict__ VT) {
  __shared__ __align__(16) bf16_t tile[64][72];
  int s0 = blockIdx.x * 64, bh = blockIdx.y;
  int b = bh >> 4, h = bh & 15;
  int t = threadIdx.x;
#pragma unroll
  for (int it = 0; it < 2; ++it) {
    int sl = (t >> 3) + it * 32, d0 = (t & 7) << 3;
    *(bf16x8*)&tile[sl][d0] =
        *(const bf16x8*)(Vin + (size_t)(b * S + s0 + sl) * DIM + h * HD + d0);
  }
  __syncthreads();
  int d = t >> 2, c0 = (t & 3) * 16;
  bf16_t buf[16];
#pragma unroll
  for (int j = 0; j < 16; ++j) buf[j] = tile[c0 + j][d];
  bf16_t* op = VT + ((size_t)bh * HD + d) * S + s0 + c0;
  *(bf16x8*)op = *(bf16x8*)&buf[0];
  *(bf16x8*)(op + 8) = *(bf16x8*)&buf[8];
}

// ---------------------------------------------------------------------------
// NT GEMM: Out[m][n] = sum_k A[m][k] * Bw[n][k] + bias[n].
// 128x128 tile, BK=32, 4 waves each 64x64 (4x4 of 16x16x32 MFMA).
// grid.z selects among up to 3 (B,bias,Out) triples (fused QKV).
template <bool OUTF32>
__global__ __launch_bounds__(256) void k_gemm(
    const bf16_t* __restrict__ A,
    const bf16_t* __restrict__ B0, const bf16_t* __restrict__ B1,
    const bf16_t* __restrict__ B2,
    const float* __restrict__ c0, const float* __restrict__ c1,
    const float* __restrict__ c2,
    void* O0, void* O1, void* O2, int Mg, int Ng, int Kg) {
  const bf16_t* Bw = blockIdx.z == 0 ? B0 : (blockIdx.z == 1 ? B1 : B2);
  const float* bias = blockIdx.z == 0 ? c0 : (blockIdx.z == 1 ? c1 : c2);
  void* Ov = blockIdx.z == 0 ? O0 : (blockIdx.z == 1 ? O1 : O2);

  __shared__ __align__(16) bf16_t Al[128 * 32];
  __shared__ __align__(16) bf16_t Bl[128 * 32];
  const int t = threadIdx.x, w = t >> 6, l = t & 63;
  const int lr = l & 15, lc = l >> 4;
  const int m0 = blockIdx.y * 128, n0 = blockIdx.x * 128;
  const int wr = w >> 1, wc = w & 1;
  f32x4 acc[4][4] = {};

  for (int k0 = 0; k0 < Kg; k0 += 32) {
    __syncthreads();
#pragma unroll
    for (int ld = 0; ld < 2; ++ld) {
      int c = t + ld * 256;            // 16B chunk id; row=c>>2, col8=(c&3)*8
      int row = c >> 2, j = (c & 3) << 3;
      bf16_t* dstA = Al + (size_t)(w * 64 + ld * 256) * 8;
      bf16_t* dstB = Bl + (size_t)(w * 64 + ld * 256) * 8;
      gl_lds16(A + (size_t)(m0 + row) * Kg + k0 + j, dstA);
      gl_lds16(Bw + (size_t)(n0 + row) * Kg + k0 + j, dstB);
    }
    __syncthreads();
    bf16x8 af[4], bfr[4];
#pragma unroll
    for (int mi = 0; mi < 4; ++mi)
      af[mi] = *(const bf16x8*)(Al + (wr * 64 + mi * 16 + lr) * 32 + lc * 8);
#pragma unroll
    for (int ni = 0; ni < 4; ++ni)
      bfr[ni] = *(const bf16x8*)(Bl + (wc * 64 + ni * 16 + lr) * 32 + lc * 8);
#pragma unroll
    for (int mi = 0; mi < 4; ++mi)
#pragma unroll
      for (int ni = 0; ni < 4; ++ni)
        acc[mi][ni] = mfma16(af[mi], bfr[ni], acc[mi][ni]);
  }

#pragma unroll
  for (int ni = 0; ni < 4; ++ni) {
    int col = n0 + wc * 64 + ni * 16 + lr;
    float bv = bias[col];
#pragma unroll
    for (int mi = 0; mi < 4; ++mi) {
#pragma unroll
      for (int r = 0; r < 4; ++r) {
        int row = m0 + wr * 64 + mi * 16 + lc * 4 + r;
        float v = acc[mi][ni][r] + bv;
        if (OUTF32)
          ((float*)Ov)[(size_t)row * Ng + col] = v;
        else
          ((bf16_t*)Ov)[(size_t)row * Ng + col] = (bf16_t)v;
      }
    }
  }
}

// ---------------------------------------------------------------------------
// Causal flash attention, R4 (R3 + mask fix).
// Block = pair of q-tiles (a, 31-a) -> uniform 33 KV iterations. Swapped
// QK^T: s = mfma(K_frag, Q_frag); lane (lr,lc) holds S[q = w*16+lr]
// [k = ni*16 + lc*4 + r] -> in-lane softmax + 2 shfl_xor. Defer-max THR=8.
// P packed to LDS b64 (swizzled), read back as PV A-frag b128. K/V
// double-buffered via global_load_lds, counted vmcnt. XCD-aware remap.
DEVFN void stage_kv(const bf16_t* __restrict__ Kc,
                    const bf16_t* __restrict__ VT, bf16_t* Kb, bf16_t* Vb,
                    int b, int bh, int h, int k0, int t, int w) {
#pragma unroll
  for (int ld = 0; ld < 2; ++ld) {
    int c = t + ld * 256;             // chunk: row=c>>3, in-row chunk=c&7
    int row = c >> 3;
    int j = ((c & 7) ^ (row & 7)) << 3;   // pre-swizzled source chunk
    bf16_t* dstK = Kb + (size_t)(w * 64 + ld * 256) * 8;
    bf16_t* dstV = Vb + (size_t)(w * 64 + ld * 256) * 8;
    gl_lds16(Kc + (size_t)(b * S + k0 + row) * DIM + h * HD + j, dstK);
    gl_lds16(VT + ((size_t)bh * HD + row) * S + k0 + j, dstV);
  }
}

__global__ __launch_bounds__(256) void k_attn(const bf16_t* __restrict__ Q,
                                              const bf16_t* __restrict__ Kc,
                                              const bf16_t* __restrict__ VT,
                                              bf16_t* __restrict__ O) {
  __shared__ __align__(16) bf16_t Kl[2][64 * 64];
  __shared__ __align__(16) bf16_t Vl[2][64 * 64];
  __shared__ __align__(16) bf16_t Pl[4][16 * 64];
  const int t = threadIdx.x, w = t >> 6, l = t & 63;
  const int lr = l & 15, lc = l >> 4;
  // XCD-aware remap: linear id -> (xcd, slot); each XCD gets 4 heads x 16 pairs
  const int lid = blockIdx.x + (blockIdx.y << 4);
  const int xcd = lid & 7, slot = lid >> 3;
  const int bh = xcd * 4 + (slot >> 4);
  const int a = slot & 15;
  const int b = bh >> 4, h = bh & 15;
  char* Pw = (char*)&Pl[w][0];

#pragma unroll 1
  for (int pi = 0; pi < 2; ++pi) {
    const int tile = (pi == 0) ? a : 31 - a;
    const int q0 = tile * 64;
    const int nt = tile + 1;

    bf16x8 qf[2];
    {
      const bf16_t* qp =
          Q + (size_t)(b * S + q0 + w * 16 + lr) * DIM + h * HD + lc * 8;
      qf[0] = *(const bf16x8*)qp;
      qf[1] = *(const bf16x8*)(qp + 32);
    }
    f32x4 o[4] = {};
    float m_run = -INFINITY;
    float rowsum = 0.f;

    // prologue: stage tile 0, drain, barrier
    stage_kv(Kc, VT, &Kl[0][0], &Vl[0][0], b, bh, h, 0, t, w);
    asm volatile("s_waitcnt vmcnt(0)" ::: "memory");
    __builtin_amdgcn_s_barrier();
    __builtin_amdgcn_sched_barrier(0);

#pragma unroll 1
    for (int it = 0; it < nt; ++it) {
      const int cur = it & 1;
      const bf16_t* Kb = &Kl[cur][0];
      const bf16_t* Vb = &Vl[cur][0];
      if (it + 1 < nt) {
        stage_kv(Kc, VT, &Kl[cur ^ 1][0], &Vl[cur ^ 1][0], b, bh, h,
                 (it + 1) * 64, t, w);
        asm volatile("s_waitcnt vmcnt(4)" ::: "memory");
      } else {
        asm volatile("s_waitcnt vmcnt(0)" ::: "memory");
      }
      __builtin_amdgcn_s_barrier();
      __builtin_amdgcn_sched_barrier(0);

      // swapped QK^T: s[ni] = K_tile x Q^T. Lane (lr,lc) holds
      // S[q = w*16 + lr][k = ni*16 + lc*4 + r].
      f32x4 s[4] = {};
      __builtin_amdgcn_s_setprio(1);
#pragma unroll
      for (int ks = 0; ks < 2; ++ks) {
#pragma unroll
        for (int ni = 0; ni < 4; ++ni) {
          int row = ni * 16 + lr;
          int off = (ks * 64 + lc * 16) ^ ((row & 7) << 4);
          bf16x8 kf = *(const bf16x8*)((const char*)Kb + row * 128 + off);
          s[ni] = mfma16(kf, qf[ks], s[ni]);
        }
      }
      __builtin_amdgcn_s_setprio(0);

      if (it == tile) {  // diagonal tile: mask k_local > q_local (= w*16+lr)
        const int qloc = w * 16 + lr;
#pragma unroll
        for (int ni = 0; ni < 4; ++ni)
#pragma unroll
          for (int r = 0; r < 4; ++r)
            if (ni * 16 + lc * 4 + r > qloc) s[ni][r] = -INFINITY;
      }

      // in-lane row max (q = w*16+lr), then reduce across the 4 lc replicas
      float pm = s[0][0];
#pragma unroll
      for (int ni = 0; ni < 4; ++ni)
#pragma unroll
        for (int r = 0; r < 4; ++r) pm = fmaxf(pm, s[ni][r]);
      pm = fmaxf(pm, __shfl_xor(pm, 16));
      pm = fmaxf(pm, __shfl_xor(pm, 32));

      // defer-max: rescale only if some row's max grew past THR=8
      if (__ballot(pm > m_run + 8.f)) {
        float mn = fmaxf(m_run, pm);
        float alpha = __expf(m_run - mn);
        m_run = mn;
        rowsum *= alpha;
#pragma unroll
        for (int r = 0; r < 4; ++r) {
          float aq = __shfl(alpha, lc * 4 + r);
#pragma unroll
          for (int ni = 0; ni < 4; ++ni) o[ni][r] *= aq;
        }
      }

      // P = exp(s - m_run); in-lane partial sum; pack to LDS as b64
      float rs = 0.f;
#pragma unroll
      for (int ni = 0; ni < 4; ++ni) {
        float p0 = __expf(s[ni][0] - m_run);
        float p1 = __expf(s[ni][1] - m_run);
        float p2 = __expf(s[ni][2] - m_run);
        float p3 = __expf(s[ni][3] - m_run);
        rs += (p0 + p1) + (p2 + p3);
        bf16x4 pb = { (bf16_t)p0, (bf16_t)p1, (bf16_t)p2, (bf16_t)p3 };
        *(bf16x4*)(Pw + (lr * 128 + ((ni * 32 + lc * 8) ^ ((lr & 7) << 4)))) =
            pb;
      }
      rs += __shfl_xor(rs, 16);
      rs += __shfl_xor(rs, 32);
      rowsum += rs;

      // PV: o[ni] += P(16x64) * V(64x64). pa = P[q=lr][ks*32 + lc*8 .. +7]
      __builtin_amdgcn_s_setprio(1);
#pragma unroll
      for (int ks = 0; ks < 2; ++ks) {
        int off = ks * 64 + lc * 16;
        bf16x8 pa =
            *(const bf16x8*)(Pw + lr * 128 + (off ^ ((lr & 7) << 4)));
#pragma unroll
        for (int ni = 0; ni < 4; ++ni) {
          int vrow = ni * 16 + lr;
          bf16x8 vb = *(const bf16x8*)((const char*)Vb + vrow * 128 +
                                       (off ^ ((vrow & 7) << 4)));
          o[ni] = mfma16(pa, vb, o[ni]);
        }
      }
      __builtin_amdgcn_s_setprio(0);

      __builtin_amdgcn_s_barrier();   // compute done before next stage overwrite
    }

    // normalize + store. o[ni] D-layout: q = q0 + w*16 + lc*4 + r, d = ni*16+lr
    float inv[4];
#pragma unroll
    for (int r = 0; r < 4; ++r) inv[r] = 1.0f / __shfl(rowsum, lc * 4 + r);
#pragma unroll
    for (int ni = 0; ni < 4; ++ni)
#pragma unroll
      for (int r = 0; r < 4; ++r) {
        int qr = q0 + w * 16 + lc * 4 + r;
        float v = o[ni][r] * inv[r];
        O[(size_t)(b * S + qr) * DIM + h * HD + ni * 16 + lr] = (bf16_t)v;
      }
  }
}

// ---------------------------------------------------------------------------
extern "C" void kernel_launch(void* const* d_in, const int* in_sizes, int n_in,
                              void* d_out, int out_size, void* d_ws,
                              size_t ws_size, hipStream_t stream) {
  const float* x  = (const float*)d_in[0];
  const float* wq = (const float*)d_in[1];
  const float* bq = (const float*)d_in[2];
  const float* wk = (const float*)d_in[3];
  const float* bk = (const float*)d_in[4];
  const float* wv = (const float*)d_in[5];
  const float* bv = (const float*)d_in[6];
  const float* wo = (const float*)d_in[7];
  const float* bo = (const float*)d_in[8];

  const size_t MD = (size_t)Mrows * DIM;   // 4194304
  const size_t WD = (size_t)DIM * DIM;     // 1048576
  bf16_t* W = (bf16_t*)d_ws;
  bf16_t* x_bf  = W;
  bf16_t* wq_bf = x_bf + MD;
  bf16_t* wk_bf = wq_bf + WD;
  bf16_t* wv_bf = wk_bf + WD;
  bf16_t* wo_bf = wv_bf + WD;
  bf16_t* q_lin = wo_bf + WD;
  bf16_t* k_lin = q_lin + MD;
  bf16_t* v_lin = k_lin + MD;
  bf16_t* vT    = v_lin + MD;
  float2* tab   = (float2*)(vT + MD);
  bf16_t* attn_out = v_lin;  // reuse: v_lin dead after transpose

  k_cvt<<<4096, 256, 0, stream>>>(x, x_bf, (int)MD);
  k_cvt<<<1024, 256, 0, stream>>>(wq, wq_bf, (int)WD);
  k_cvt<<<1024, 256, 0, stream>>>(wk, wk_bf, (int)WD);
  k_cvt<<<1024, 256, 0, stream>>>(wv, wv_bf, (int)WD);
  k_cvt<<<1024, 256, 0, stream>>>(wo, wo_bf, (int)WD);
  k_tab<<<256, 256, 0, stream>>>(tab);

  // fused QKV projections
  k_gemm<false><<<dim3(DIM / 128, Mrows / 128, 3), 256, 0, stream>>>(
      x_bf, wq_bf, wk_bf, wv_bf, bq, bk, bv, q_lin, k_lin, v_lin, Mrows, DIM,
      DIM);

  k_rope<<<2048, 256, 0, stream>>>(q_lin, tab, 0.125f);  // fold 1/sqrt(64)
  k_rope<<<2048, 256, 0, stream>>>(k_lin, tab, 1.0f);
  k_trans<<<dim3(S / 64, Bn * NH), 256, 0, stream>>>(v_lin, vT);

  k_attn<<<dim3(16, Bn * NH), 256, 0, stream>>>(q_lin, k_lin, vT, attn_out);

  // output projection, fp32 out + bias straight to d_out
  k_gemm<true><<<dim3(DIM / 128, Mrows / 128, 1), 256, 0, stream>>>(
      attn_out, wo_bf, wo_bf, wo_bf, bo, bo, bo, d_out, d_out, d_out, Mrows,
      DIM, DIM);
}